// Round 1
// baseline (683.665 us; speedup 1.0000x reference)
//
#include <hip/hip_runtime.h>

// GeneralLinear: x[8192,16,576] fp32, three per-irrep linears (m=64, l=0,1,2)
// out[8192,16,9] fp32.  Memory-bound: 302 MB x-read, floor ~49 us.
#define NROWS 8192
#define CIN   16
#define DIN   576
#define COUT  16

// Transpose weights into wt[l][o][k] (k = c*64+u, contiguous) so each lane
// (fixed o) can read its weight column with float4 loads.
// wt size = 3*16*1024 floats = 192 KB in d_ws.
__global__ void transpose_w_kernel(const float* __restrict__ w0,
                                   const float* __restrict__ w1,
                                   const float* __restrict__ w2,
                                   float* __restrict__ wt) {
    int idx = blockIdx.x * 256 + threadIdx.x;   // 0..49151
    int l = idx >> 14;                          // 16384 entries per l
    int r = idx & 16383;
    int o = r >> 10;
    int k = r & 1023;
    const float* w = (l == 0) ? w0 : (l == 1) ? w1 : w2;
    wt[idx] = w[k * 16 + o];                    // write coalesced
}

// g (blockIdx.x & 1) == 0: computes l=0 (col 0) and l=1 (cols 1..3)
//                     == 1: computes l=2 (cols 4..8)
// Thread = (row, o).  16 lanes per row share x addresses (coalescer dedups).
template <bool TW>
__global__ __launch_bounds__(256, 4) void general_linear_kernel(
    const float* __restrict__ x,
    const float* __restrict__ w0,
    const float* __restrict__ w1,
    const float* __restrict__ w2,
    const float* __restrict__ wt,
    float* __restrict__ out) {
    const int tid = threadIdx.x;
    const int o   = tid & 15;
    const int g   = blockIdx.x & 1;
    const int r   = (blockIdx.x >> 1) * 16 + (tid >> 4);

    const float* xr = x + (size_t)r * (CIN * DIN);
    float* op = out + ((size_t)r * COUT + o) * 9;
    const float s = 1.0f / 32.0f;   // 1/sqrt(fan_in), fan_in = 16*64

    if (g == 0) {
        float a0 = 0.f, a1x = 0.f, a1y = 0.f, a1z = 0.f;
        for (int c = 0; c < CIN; ++c) {
            const float4* xv0 = (const float4*)(xr + c * DIN);        // l=0: 16 f4
            const float4* xv1 = (const float4*)(xr + c * DIN + 64);   // l=1: 48 f4
            const float4* wv0 = nullptr;
            const float4* wv1 = nullptr;
            const float*  w0p = nullptr;
            const float*  w1p = nullptr;
            if constexpr (TW) {
                wv0 = (const float4*)(wt + o * 1024 + c * 64);
                wv1 = (const float4*)(wt + 16384 + o * 1024 + c * 64);
            } else {
                w0p = w0 + (c * 64) * 16 + o;
                w1p = w1 + (c * 64) * 16 + o;
            }
            // ---- l = 0: j = u, weight wq lane-compile-time offsets ----
#pragma unroll
            for (int q = 0; q < 16; ++q) {
                float4 wq;
                if constexpr (TW) { wq = wv0[q]; }
                else {
                    wq.x = w0p[(4 * q + 0) * 16];
                    wq.y = w0p[(4 * q + 1) * 16];
                    wq.z = w0p[(4 * q + 2) * 16];
                    wq.w = w0p[(4 * q + 3) * 16];
                }
                float4 xq = xv0[q];
                a0 += xq.x * wq.x;
                a0 += xq.y * wq.y;
                a0 += xq.z * wq.z;
                a0 += xq.w * wq.w;
            }
            // ---- l = 1: 192 elems, u = j/3, e = j%3; 12 elems per q ----
#pragma unroll
            for (int q = 0; q < 16; ++q) {
                float4 wq;
                if constexpr (TW) { wq = wv1[q]; }
                else {
                    wq.x = w1p[(4 * q + 0) * 16];
                    wq.y = w1p[(4 * q + 1) * 16];
                    wq.z = w1p[(4 * q + 2) * 16];
                    wq.w = w1p[(4 * q + 3) * 16];
                }
                float4 xa = xv1[q * 3 + 0];
                float4 xb = xv1[q * 3 + 1];
                float4 xc = xv1[q * 3 + 2];
                // u = 4q+0
                a1x += xa.x * wq.x; a1y += xa.y * wq.x; a1z += xa.z * wq.x;
                // u = 4q+1
                a1x += xa.w * wq.y; a1y += xb.x * wq.y; a1z += xb.y * wq.y;
                // u = 4q+2
                a1x += xb.z * wq.z; a1y += xb.w * wq.z; a1z += xc.x * wq.z;
                // u = 4q+3
                a1x += xc.y * wq.w; a1y += xc.z * wq.w; a1z += xc.w * wq.w;
            }
        }
        op[0] = a0 * s;
        op[1] = a1x * s;
        op[2] = a1y * s;
        op[3] = a1z * s;
    } else {
        float b0 = 0.f, b1 = 0.f, b2 = 0.f, b3 = 0.f, b4 = 0.f;
        for (int c = 0; c < CIN; ++c) {
            const float4* xv2 = (const float4*)(xr + c * DIN + 256);  // l=2: 80 f4
            const float4* wv2 = nullptr;
            const float*  w2p = nullptr;
            if constexpr (TW) {
                wv2 = (const float4*)(wt + 32768 + o * 1024 + c * 64);
            } else {
                w2p = w2 + (c * 64) * 16 + o;
            }
            // ---- l = 2: 320 elems, u = j/5, e = j%5; 20 elems per q ----
#pragma unroll
            for (int q = 0; q < 16; ++q) {
                float4 wq;
                if constexpr (TW) { wq = wv2[q]; }
                else {
                    wq.x = w2p[(4 * q + 0) * 16];
                    wq.y = w2p[(4 * q + 1) * 16];
                    wq.z = w2p[(4 * q + 2) * 16];
                    wq.w = w2p[(4 * q + 3) * 16];
                }
                float4 xa = xv2[q * 5 + 0];
                float4 xb = xv2[q * 5 + 1];
                float4 xc = xv2[q * 5 + 2];
                float4 xd = xv2[q * 5 + 3];
                float4 xe = xv2[q * 5 + 4];
                // u = 4q+0 : e = 0..4
                b0 += xa.x * wq.x; b1 += xa.y * wq.x; b2 += xa.z * wq.x;
                b3 += xa.w * wq.x; b4 += xb.x * wq.x;
                // u = 4q+1
                b0 += xb.y * wq.y; b1 += xb.z * wq.y; b2 += xb.w * wq.y;
                b3 += xc.x * wq.y; b4 += xc.y * wq.y;
                // u = 4q+2
                b0 += xc.z * wq.z; b1 += xc.w * wq.z; b2 += xd.x * wq.z;
                b3 += xd.y * wq.z; b4 += xd.z * wq.z;
                // u = 4q+3
                b0 += xd.w * wq.w; b1 += xe.x * wq.w; b2 += xe.y * wq.w;
                b3 += xe.z * wq.w; b4 += xe.w * wq.w;
            }
        }
        op[4] = b0 * s;
        op[5] = b1 * s;
        op[6] = b2 * s;
        op[7] = b3 * s;
        op[8] = b4 * s;
    }
}

extern "C" void kernel_launch(void* const* d_in, const int* in_sizes, int n_in,
                              void* d_out, int out_size, void* d_ws, size_t ws_size,
                              hipStream_t stream) {
    const float* x  = (const float*)d_in[0];
    const float* w0 = (const float*)d_in[1];
    const float* w1 = (const float*)d_in[2];
    const float* w2 = (const float*)d_in[3];
    float* out = (float*)d_out;

    const size_t wt_bytes = 3 * 16384 * sizeof(float);  // 192 KB
    const bool tw = (d_ws != nullptr) && (ws_size >= wt_bytes);

    // grid: 512 row-blocks x 2 col-groups, interleaved; 256 threads = 16 rows x 16 o
    const int grid = (NROWS / 16) * 2;

    if (tw) {
        float* wt = (float*)d_ws;
        transpose_w_kernel<<<192, 256, 0, stream>>>(w0, w1, w2, wt);
        general_linear_kernel<true><<<grid, 256, 0, stream>>>(x, w0, w1, w2, wt, out);
    } else {
        general_linear_kernel<false><<<grid, 256, 0, stream>>>(x, w0, w1, w2, nullptr, out);
    }
}

// Round 2
// 498.205 us; speedup vs baseline: 1.3723x; 1.3723x over previous
//
#include <hip/hip_runtime.h>

// GeneralLinear: x[8192,16,576] fp32 -> out[8192,16,9] fp32.
// out[n,o,col_l(e)] = (1/32) * sum_{c,u} x[n, c, off_l + u*d_l + e] * w_l[c*64+u, o]
//
// Memory-bound: 302 MB x read once; HBM floor ~49 us.
// Lane map: lane = r(0..15) + 16*oq(0..3); thread computes a float4 over
// o = 4*oq..4*oq+3.  Wave w = tid>>6 owns c-quarter [4w, 4w+4).
//   - x loads: 16 unique rows x 16 B per instr (256 B unique, 4x round-1)
//   - w loads: w[k*16 + 4*oq] float4 -> the 4 oq segments are ONE 64B line
//     (original layout, no transpose kernel needed)
// Partials reduced across the 4 waves via LDS, then scattered b32 stores.
// blockIdx&1 selects col group: g0 = l0+l1 (cols 0..3), g1 = l2 (cols 4..8).

#define NROWS 8192
#define CIN   16
#define DIN   576

__device__ __forceinline__ void fma4(float4& a, float s, float4 w) {
    a.x += s * w.x;
    a.y += s * w.y;
    a.z += s * w.z;
    a.w += s * w.w;
}

__global__ __launch_bounds__(256, 4) void glin_kernel(
    const float* __restrict__ x,
    const float* __restrict__ w0,
    const float* __restrict__ w1,
    const float* __restrict__ w2,
    float* __restrict__ out) {
    const int tid  = threadIdx.x;
    const int lane = tid & 63;
    const int wv   = tid >> 6;        // c-quarter 0..3
    const int r    = lane & 15;       // row within block tile
    const int oq   = lane >> 4;       // o-quad 0..3
    const int g    = blockIdx.x & 1;  // 0: cols 0..3 (l=0,1)  1: cols 4..8 (l=2)
    const int rg   = (blockIdx.x >> 1) * 16 + r;

    const float* xr = x + (size_t)rg * (CIN * DIN);

    __shared__ float4 red[4][5][64];  // [wave][col][lane] - contiguous b128 pattern

    float4 acc[5];
#pragma unroll
    for (int i = 0; i < 5; ++i) acc[i] = make_float4(0.f, 0.f, 0.f, 0.f);

    const int c0 = wv * 4;

    if (g == 0) {
        for (int cc = 0; cc < 4; ++cc) {
            const int c = c0 + cc;
            const float4* xv0 = (const float4*)(xr + c * DIN);        // l0: 16 f4
            const float4* xv1 = (const float4*)(xr + c * DIN + 64);   // l1: 48 f4
            const float*  p0  = w0 + (c * 64) * 16 + 4 * oq;
            const float*  p1  = w1 + (c * 64) * 16 + 4 * oq;
#pragma unroll
            for (int q = 0; q < 16; ++q) {
                // ---- l = 0 (col 0): u = 4q..4q+3 ----
                float4 xq = xv0[q];
                float4 a0 = *(const float4*)(p0 + (4 * q + 0) * 16);
                float4 a1 = *(const float4*)(p0 + (4 * q + 1) * 16);
                float4 a2 = *(const float4*)(p0 + (4 * q + 2) * 16);
                float4 a3 = *(const float4*)(p0 + (4 * q + 3) * 16);
                fma4(acc[0], xq.x, a0);
                fma4(acc[0], xq.y, a1);
                fma4(acc[0], xq.z, a2);
                fma4(acc[0], xq.w, a3);
                // ---- l = 1 (cols 1..3): u = 4q..4q+3, e = 0..2 ----
                float4 xa = xv1[3 * q + 0];
                float4 xb = xv1[3 * q + 1];
                float4 xc = xv1[3 * q + 2];
                float4 b0 = *(const float4*)(p1 + (4 * q + 0) * 16);
                float4 b1 = *(const float4*)(p1 + (4 * q + 1) * 16);
                float4 b2 = *(const float4*)(p1 + (4 * q + 2) * 16);
                float4 b3 = *(const float4*)(p1 + (4 * q + 3) * 16);
                fma4(acc[1], xa.x, b0); fma4(acc[2], xa.y, b0); fma4(acc[3], xa.z, b0);
                fma4(acc[1], xa.w, b1); fma4(acc[2], xb.x, b1); fma4(acc[3], xb.y, b1);
                fma4(acc[1], xb.z, b2); fma4(acc[2], xb.w, b2); fma4(acc[3], xc.x, b2);
                fma4(acc[1], xc.y, b3); fma4(acc[2], xc.z, b3); fma4(acc[3], xc.w, b3);
            }
        }
    } else {
        for (int cc = 0; cc < 4; ++cc) {
            const int c = c0 + cc;
            const float4* xv2 = (const float4*)(xr + c * DIN + 256);  // l2: 80 f4
            const float*  p2  = w2 + (c * 64) * 16 + 4 * oq;
#pragma unroll
            for (int q = 0; q < 16; ++q) {
                float4 xa = xv2[5 * q + 0];
                float4 xb = xv2[5 * q + 1];
                float4 xc = xv2[5 * q + 2];
                float4 xd = xv2[5 * q + 3];
                float4 xe = xv2[5 * q + 4];
                float4 c0w = *(const float4*)(p2 + (4 * q + 0) * 16);
                float4 c1w = *(const float4*)(p2 + (4 * q + 1) * 16);
                float4 c2w = *(const float4*)(p2 + (4 * q + 2) * 16);
                float4 c3w = *(const float4*)(p2 + (4 * q + 3) * 16);
                // u = 4q+0: e = 0..4
                fma4(acc[0], xa.x, c0w); fma4(acc[1], xa.y, c0w); fma4(acc[2], xa.z, c0w);
                fma4(acc[3], xa.w, c0w); fma4(acc[4], xb.x, c0w);
                // u = 4q+1
                fma4(acc[0], xb.y, c1w); fma4(acc[1], xb.z, c1w); fma4(acc[2], xb.w, c1w);
                fma4(acc[3], xc.x, c1w); fma4(acc[4], xc.y, c1w);
                // u = 4q+2
                fma4(acc[0], xc.z, c2w); fma4(acc[1], xc.w, c2w); fma4(acc[2], xd.x, c2w);
                fma4(acc[3], xd.y, c2w); fma4(acc[4], xd.z, c2w);
                // u = 4q+3
                fma4(acc[0], xd.w, c3w); fma4(acc[1], xe.x, c3w); fma4(acc[2], xe.y, c3w);
                fma4(acc[3], xe.z, c3w); fma4(acc[4], xe.w, c3w);
            }
        }
    }

    // ---- cross-wave reduction of c-quarters via LDS ----
#pragma unroll
    for (int col = 0; col < 5; ++col) red[wv][col][lane] = acc[col];
    __syncthreads();

    // 256 threads: thread = (r, o); gather 4 partials, scale, store.
    const int rr = tid & 15;
    const int oo = tid >> 4;                 // 0..15
    const int ln = rr + 16 * (oo >> 2);      // source lane
    const int cm = oo & 3;                   // float4 component
    const float s = 1.0f / 32.0f;
    float* op = out + ((size_t)((blockIdx.x >> 1) * 16 + rr) * 16 + oo) * 9 + (g ? 4 : 0);
    const int nc = g ? 5 : 4;
    for (int col = 0; col < nc; ++col) {
        float v = ((const float*)&red[0][col][ln])[cm]
                + ((const float*)&red[1][col][ln])[cm]
                + ((const float*)&red[2][col][ln])[cm]
                + ((const float*)&red[3][col][ln])[cm];
        op[col] = v * s;
    }
}

extern "C" void kernel_launch(void* const* d_in, const int* in_sizes, int n_in,
                              void* d_out, int out_size, void* d_ws, size_t ws_size,
                              hipStream_t stream) {
    const float* x  = (const float*)d_in[0];
    const float* w0 = (const float*)d_in[1];
    const float* w1 = (const float*)d_in[2];
    const float* w2 = (const float*)d_in[3];
    float* out = (float*)d_out;

    // 512 row-tiles (16 rows each) x 2 col-groups
    const int grid = (NROWS / 16) * 2;
    glin_kernel<<<grid, 256, 0, stream>>>(x, w0, w1, w2, out);
}

// Round 3
// 478.800 us; speedup vs baseline: 1.4279x; 1.0405x over previous
//
#include <hip/hip_runtime.h>

// GeneralLinear: x[8192,16,576] fp32 -> out[8192,16,9] fp32.
// out[n,o,col_l(e)] = (1/32) * sum_{c,u} x[n, c, off_l + u*d_l + e] * w_l[c*64+u, o]
//
// Structure (R3): block = (64-row tile, c-quarter cq, group g).
//   g=0 -> cols 0..3 (l=0 region x[...,0:256], weights w0+w1, 32 KB LDS)
//   g=1 -> cols 4..8 (l=2 region x[...,256:576], weights w2, 16 KB LDS)
// The 8 (cq,g) combos exactly partition each x row -> x read once from HBM.
// Weights live in LDS (ds_read_b128, broadcast over 16 row-lanes, no conflicts).
// x is the only VMEM stream, software-pipelined one batch ahead (ping-pong bufs).
// Per-block partials -> ws[cq][col][n][o] (float4 stores), reduced by glin_reduce.

#define NROWS 8192
#define CIN   16
#define DIN   576
#define PLANE (NROWS * 16)   // 131072 floats per [col][n][o] plane

__device__ __forceinline__ void fma4(float4& a, float s, const float4 w) {
    a.x += s * w.x; a.y += s * w.y; a.z += s * w.z; a.w += s * w.w;
}
__device__ __forceinline__ float4 ld4(const float* p) { return *(const float4*)p; }

template <bool ATOMIC>
__global__ __launch_bounds__(256, 4) void glin_main(
    const float* __restrict__ x,
    const float* __restrict__ w0,
    const float* __restrict__ w1,
    const float* __restrict__ w2,
    float* __restrict__ dst)   // ATOMIC ? out : ws partials
{
    __shared__ float lw[8192];   // 32 KB: g0 = [w0 slice | w1 slice], g1 = [w2 slice]
    const int tid  = threadIdx.x;
    const int b    = blockIdx.x;
    const int tile = b & 127;
    const int cq   = (b >> 7) & 3;
    const int g    = b >> 9;

    // ---- stage weight slice (k = cq*256 .. +256, all 16 o) into LDS ----
    {
        float4* d = (float4*)lw;
        if (g == 0) {
            const float4* s0 = (const float4*)(w0 + cq * 4096);
            const float4* s1 = (const float4*)(w1 + cq * 4096);
            for (int i = tid; i < 1024; i += 256) { d[i] = s0[i]; d[1024 + i] = s1[i]; }
        } else {
            const float4* s2 = (const float4*)(w2 + cq * 4096);
            for (int i = tid; i < 1024; i += 256) d[i] = s2[i];
        }
    }
    __syncthreads();

    const int lane = tid & 63;
    const int wv   = tid >> 6;        // wave id -> 16-row subtile
    const int r    = lane & 15;
    const int oq   = lane >> 4;       // output quad: o = 4*oq .. 4*oq+3
    const int n    = tile * 64 + wv * 16 + r;
    const float* xr = x + (size_t)n * (CIN * DIN) + cq * 4 * DIN + (g ? 256 : 0);

    float4 acc[5];
#pragma unroll
    for (int i = 0; i < 5; ++i) acc[i] = make_float4(0.f, 0.f, 0.f, 0.f);

    if (g == 0) {
        // t = 0..31: cc = t>>3 (channel within quarter), q-pair qa = 2*(t&7)
        float4 bufA[8], bufB[8];
        auto loadx = [&](int t, float4* dv) {
            const float* base = xr + (t >> 3) * DIN;
            const int qa = (t & 7) * 2;
            dv[0] = ld4(base + 4 * qa);
            dv[1] = ld4(base + 4 * qa + 4);
            const float* p1 = base + 64 + 12 * qa;
            dv[2] = ld4(p1);      dv[3] = ld4(p1 + 4);  dv[4] = ld4(p1 + 8);
            dv[5] = ld4(p1 + 12); dv[6] = ld4(p1 + 16); dv[7] = ld4(p1 + 20);
        };
        auto comp = [&](int t, const float4* cx) {
            const float* l0 = lw + t * 128 + 4 * oq;
            const float* l1 = l0 + 4096;
            // l=0, q = qa (u = 8(t&7)+0..3) and q = qa+1 (u +4..7)
            fma4(acc[0], cx[0].x, ld4(l0));       fma4(acc[0], cx[0].y, ld4(l0 + 16));
            fma4(acc[0], cx[0].z, ld4(l0 + 32));  fma4(acc[0], cx[0].w, ld4(l0 + 48));
            fma4(acc[0], cx[1].x, ld4(l0 + 64));  fma4(acc[0], cx[1].y, ld4(l0 + 80));
            fma4(acc[0], cx[1].z, ld4(l0 + 96));  fma4(acc[0], cx[1].w, ld4(l0 + 112));
            // l=1, q = qa: xa=cx[2] xb=cx[3] xc=cx[4]
            float4 b0 = ld4(l1),      b1 = ld4(l1 + 16), b2 = ld4(l1 + 32), b3 = ld4(l1 + 48);
            fma4(acc[1], cx[2].x, b0); fma4(acc[2], cx[2].y, b0); fma4(acc[3], cx[2].z, b0);
            fma4(acc[1], cx[2].w, b1); fma4(acc[2], cx[3].x, b1); fma4(acc[3], cx[3].y, b1);
            fma4(acc[1], cx[3].z, b2); fma4(acc[2], cx[3].w, b2); fma4(acc[3], cx[4].x, b2);
            fma4(acc[1], cx[4].y, b3); fma4(acc[2], cx[4].z, b3); fma4(acc[3], cx[4].w, b3);
            // l=1, q = qa+1: xa=cx[5] xb=cx[6] xc=cx[7]
            float4 b4 = ld4(l1 + 64), b5 = ld4(l1 + 80), b6 = ld4(l1 + 96), b7 = ld4(l1 + 112);
            fma4(acc[1], cx[5].x, b4); fma4(acc[2], cx[5].y, b4); fma4(acc[3], cx[5].z, b4);
            fma4(acc[1], cx[5].w, b5); fma4(acc[2], cx[6].x, b5); fma4(acc[3], cx[6].y, b5);
            fma4(acc[1], cx[6].z, b6); fma4(acc[2], cx[6].w, b6); fma4(acc[3], cx[7].x, b6);
            fma4(acc[1], cx[7].y, b7); fma4(acc[2], cx[7].z, b7); fma4(acc[3], cx[7].w, b7);
        };
        loadx(0, bufA);
        for (int t = 0; t < 30; t += 2) {
            loadx(t + 1, bufB);
            comp(t, bufA);
            loadx(t + 2, bufA);
            comp(t + 1, bufB);
        }
        loadx(31, bufB);
        comp(30, bufA);
        comp(31, bufB);
    } else {
        // t = 0..63: cc = t>>4, q = t&15
        float4 bufA[5], bufB[5];
        auto loadx = [&](int t, float4* dv) {
            const float* base = xr + (t >> 4) * DIN + (t & 15) * 20;
            dv[0] = ld4(base);      dv[1] = ld4(base + 4);  dv[2] = ld4(base + 8);
            dv[3] = ld4(base + 12); dv[4] = ld4(base + 16);
        };
        auto comp = [&](int t, const float4* cx) {
            const float* l2 = lw + t * 64 + 4 * oq;
            float4 c0 = ld4(l2), c1 = ld4(l2 + 16), c2 = ld4(l2 + 32), c3 = ld4(l2 + 48);
            // u = 4q+0 : e = 0..4
            fma4(acc[0], cx[0].x, c0); fma4(acc[1], cx[0].y, c0); fma4(acc[2], cx[0].z, c0);
            fma4(acc[3], cx[0].w, c0); fma4(acc[4], cx[1].x, c0);
            // u = 4q+1
            fma4(acc[0], cx[1].y, c1); fma4(acc[1], cx[1].z, c1); fma4(acc[2], cx[1].w, c1);
            fma4(acc[3], cx[2].x, c1); fma4(acc[4], cx[2].y, c1);
            // u = 4q+2
            fma4(acc[0], cx[2].z, c2); fma4(acc[1], cx[2].w, c2); fma4(acc[2], cx[3].x, c2);
            fma4(acc[3], cx[3].y, c2); fma4(acc[4], cx[3].z, c2);
            // u = 4q+3
            fma4(acc[0], cx[3].w, c3); fma4(acc[1], cx[4].x, c3); fma4(acc[2], cx[4].y, c3);
            fma4(acc[3], cx[4].z, c3); fma4(acc[4], cx[4].w, c3);
        };
        loadx(0, bufA);
        for (int t = 0; t < 62; t += 2) {
            loadx(t + 1, bufB);
            comp(t, bufA);
            loadx(t + 2, bufA);
            comp(t + 1, bufB);
        }
        loadx(63, bufB);
        comp(62, bufA);
        comp(63, bufB);
    }

    // ---- epilogue ----
    const int nc    = g ? 5 : 4;
    const int pbase = g ? 4 : 0;
    if (!ATOMIC) {
        // ws[cq][p][n][o]: contiguous float4 store per thread
        float* wp = dst + (size_t)(cq * 9 + pbase) * PLANE + n * 16 + 4 * oq;
        for (int col = 0; col < nc; ++col)
            *(float4*)(wp + (size_t)col * PLANE) = acc[col];
    } else {
        const float s = 1.0f / 32.0f;
        float* op = dst + ((size_t)n * 16 + 4 * oq) * 9 + pbase;
        for (int col = 0; col < nc; ++col) {
            atomicAdd(op + 0 * 9 + col, acc[col].x * s);
            atomicAdd(op + 1 * 9 + col, acc[col].y * s);
            atomicAdd(op + 2 * 9 + col, acc[col].z * s);
            atomicAdd(op + 3 * 9 + col, acc[col].w * s);
        }
    }
}

__global__ __launch_bounds__(256) void glin_reduce(const float* __restrict__ ws,
                                                  float* __restrict__ out) {
    const int idx = blockIdx.x * 256 + threadIdx.x;   // (n*16 + o), 131072 total
    const float s = 1.0f / 32.0f;
    float* op = out + (size_t)idx * 9;
#pragma unroll
    for (int p = 0; p < 9; ++p) {
        const float* wp = ws + (size_t)p * PLANE + idx;
        float v = wp[0] + wp[(size_t)9 * PLANE] + wp[(size_t)18 * PLANE] + wp[(size_t)27 * PLANE];
        op[p] = v * s;
    }
}

extern "C" void kernel_launch(void* const* d_in, const int* in_sizes, int n_in,
                              void* d_out, int out_size, void* d_ws, size_t ws_size,
                              hipStream_t stream) {
    const float* x  = (const float*)d_in[0];
    const float* w0 = (const float*)d_in[1];
    const float* w1 = (const float*)d_in[2];
    const float* w2 = (const float*)d_in[3];
    float* out = (float*)d_out;

    const size_t need = (size_t)4 * 9 * PLANE * sizeof(float);   // 18.9 MB
    if (d_ws != nullptr && ws_size >= need) {
        glin_main<false><<<1024, 256, 0, stream>>>(x, w0, w1, w2, (float*)d_ws);
        glin_reduce<<<PLANE / 256, 256, 0, stream>>>((const float*)d_ws, out);
    } else {
        hipMemsetAsync(d_out, 0, (size_t)out_size * sizeof(float), stream);
        glin_main<true><<<1024, 256, 0, stream>>>(x, w0, w1, w2, out);
    }
}

// Round 4
// 443.218 us; speedup vs baseline: 1.5425x; 1.0803x over previous
//
#include <hip/hip_runtime.h>

// GeneralLinear: x[8192,16,576] fp32 -> out[8192,16,9] fp32.
// out[n,o,col_l(e)] = (1/32) * sum_{c,u} x[n, c, off_l + u*d_l + e] * w_l[c*64+u, o]
//
// R4 structure: async global_load_lds (width=16) double-buffered x staging.
// Block = (tile of 256 rows, c-pair cp in 0..7, g in 0..1), grid 512 = 2/CU.
//   g=0: x cols [0,256)  -> out cols 0..3 (l0+l1), weights w0+w1 (16 KB LDS)
//   g=1: x cols [256,576)-> out cols 4..8 (l2),    weights w2    (8 KB LDS)
// Stage = 16 rows x 1 channel; one DMA instr per row = contiguous 1 KB
// (g1: +4 gather instrs for the 256 B/row remainder). LDS row pitch 1040 B
// -> 2-way bank aliasing (free). Waves split the u-dim (q-ranges); partials
// reduced via 8 KB LDS red buffer per 16-row group; written to ws[cp][col][n][o],
// summed by glin_reduce.

#define NROWS 8192
#define CIN   16
#define DIN   576
#define XROW  (CIN * DIN)      // 9216 floats per x row
#define PLANE (NROWS * 16)     // 131072 floats per [col][n][o] plane
#define TILES 32
#define RPB   (NROWS / TILES)  // 256 rows per block
#define NSTG  32               // 16 rowgroups x 2 channels

// LDS float offsets (57856 B total, shared between both g layouts)
#define G0_XB0 0
#define G0_XB1 4160
#define G0_W   8320
#define G1_XB0 0
#define G1_XB1 5184
#define G1_W   10368
#define REDO   12416
#define LDSF   14464

__device__ __forceinline__ void dma16(const float* g, float* l) {
    __builtin_amdgcn_global_load_lds(
        (const __attribute__((address_space(1))) void*)g,
        (__attribute__((address_space(3))) void*)l, 16, 0, 0);
}

__device__ __forceinline__ void fma4(float4& a, float s, const float4 w) {
    a.x += s * w.x; a.y += s * w.y; a.z += s * w.z; a.w += s * w.w;
}

// g1 x-slice chunk cc (0..79) of row r -> LDS float index
__device__ __forceinline__ int xg1(int xb, int r, int cc) {
    return (cc < 64) ? (xb + r * 260 + cc * 4)
                     : (xb + 4160 + ((cc - 64) & 3) * 256 + ((cc - 64) >> 2) * 64 + r * 4);
}

template <bool ATOMIC>
__global__ __launch_bounds__(256, 2) void glin_main(
    const float* __restrict__ x,
    const float* __restrict__ w0,
    const float* __restrict__ w1,
    const float* __restrict__ w2,
    float* __restrict__ dst)   // ATOMIC ? out : ws partials
{
    __shared__ float lds[LDSF];
#define LD4(i) (*(const float4*)&lds[(i)])

    const int tid  = threadIdx.x;
    const int lane = tid & 63;
    const int wv   = tid >> 6;
    const int r    = lane & 15;
    const int oq   = lane >> 4;
    const int b    = blockIdx.x;
    const int tile = b & 31;
    const int cp   = (b >> 5) & 7;
    const int g    = b >> 8;
    const int rowbase = tile * RPB;
    const int qb   = wv * 4;          // this wave's q-range

    // ---- prologue: DMA weights + stage 0, one barrier ----
    if (g == 0) {
#pragma unroll
        for (int i = 0; i < 4; ++i) {
            const int t = wv * 4 + i;                       // 0..15
            const float* warr = (t < 8) ? w0 : w1;
            const int tt = t & 7;
            dma16(warr + cp * 2048 + tt * 256 + lane * 4,
                  &lds[G0_W + (t < 8 ? 0 : 2048) + tt * 256]);
        }
    } else {
#pragma unroll
        for (int i = 0; i < 2; ++i) {
            const int t = wv * 2 + i;                       // 0..7
            dma16(w2 + cp * 2048 + t * 256 + lane * 4, &lds[G1_W + t * 256]);
        }
    }

    // stage DMA issuer
    auto issue = [&](int s) {
        const int rg = s >> 1;
        const int c  = cp * 2 + (s & 1);
        if (g == 0) {
            const int xb = (s & 1) ? G0_XB1 : G0_XB0;
#pragma unroll
            for (int i = 0; i < 4; ++i) {
                const int rr = wv * 4 + i;
                dma16(x + (size_t)(rowbase + rg * 16 + rr) * XROW + c * DIN + lane * 4,
                      &lds[xb + rr * 260]);
            }
        } else {
            const int xb = (s & 1) ? G1_XB1 : G1_XB0;
#pragma unroll
            for (int i = 0; i < 4; ++i) {
                const int rr = wv * 4 + i;
                dma16(x + (size_t)(rowbase + rg * 16 + rr) * XROW + c * DIN + 256 + lane * 4,
                      &lds[xb + rr * 260]);
            }
            // remainder gather: instr m = wv, lane -> (row = lane&15, jj = lane>>4)
            const int r16 = lane & 15, jj = lane >> 4;
            dma16(x + (size_t)(rowbase + rg * 16 + r16) * XROW + c * DIN + 512 + wv * 4 + jj * 16,
                  &lds[xb + 4160 + wv * 256]);
        }
    };

    issue(0);
    __syncthreads();

    float4 acc[5];
    const int gb = g ? 4 : 0;
    float* ws = dst;

    for (int s = 0; s < NSTG; ++s) {
        const int rg  = s >> 1;
        const int cpr = s & 1;
        if (cpr == 0) {
#pragma unroll
            for (int i = 0; i < 5; ++i) acc[i] = make_float4(0.f, 0.f, 0.f, 0.f);
        }
        if (s + 1 < NSTG) issue(s + 1);

        // ---- compute stage s from buf[s&1] ----
        if (g == 0) {
            const int xb  = cpr ? G0_XB1 : G0_XB0;
            const int xro = xb + r * 260;
            const int wbo = G0_W + cpr * 1024 + oq * 4;
#pragma unroll
            for (int qq = 0; qq < 4; ++qq) {
                const int q  = qb + qq;
                const int wa = wbo + q * 64;
                // l = 0 (col 0): u = 4q..4q+3
                float4 xq = LD4(xro + 4 * q);
                float4 a0 = LD4(wa), a1 = LD4(wa + 16), a2 = LD4(wa + 32), a3 = LD4(wa + 48);
                fma4(acc[0], xq.x, a0); fma4(acc[0], xq.y, a1);
                fma4(acc[0], xq.z, a2); fma4(acc[0], xq.w, a3);
                // l = 1 (cols 1..3)
                const int x1 = xro + 64 + 12 * q;
                float4 xa = LD4(x1), xbv = LD4(x1 + 4), xc = LD4(x1 + 8);
                float4 b0 = LD4(wa + 2048), b1 = LD4(wa + 2064),
                       b2 = LD4(wa + 2080), b3 = LD4(wa + 2096);
                fma4(acc[1], xa.x, b0); fma4(acc[2], xa.y, b0); fma4(acc[3], xa.z, b0);
                fma4(acc[1], xa.w, b1); fma4(acc[2], xbv.x, b1); fma4(acc[3], xbv.y, b1);
                fma4(acc[1], xbv.z, b2); fma4(acc[2], xbv.w, b2); fma4(acc[3], xc.x, b2);
                fma4(acc[1], xc.y, b3); fma4(acc[2], xc.z, b3); fma4(acc[3], xc.w, b3);
            }
        } else {
            const int xb  = cpr ? G1_XB1 : G1_XB0;
            const int wbo = G1_W + cpr * 1024 + oq * 4;
#pragma unroll
            for (int qq = 0; qq < 4; ++qq) {
                const int q  = qb + qq;
                const int wa = wbo + q * 64;
                float4 c0 = LD4(wa), c1 = LD4(wa + 16), c2 = LD4(wa + 32), c3 = LD4(wa + 48);
                float4 xa = LD4(xg1(xb, r, 5 * q + 0));
                float4 xbv = LD4(xg1(xb, r, 5 * q + 1));
                float4 xc = LD4(xg1(xb, r, 5 * q + 2));
                float4 xd = LD4(xg1(xb, r, 5 * q + 3));
                float4 xe = LD4(xg1(xb, r, 5 * q + 4));
                fma4(acc[0], xa.x, c0); fma4(acc[1], xa.y, c0); fma4(acc[2], xa.z, c0);
                fma4(acc[3], xa.w, c0); fma4(acc[4], xbv.x, c0);
                fma4(acc[0], xbv.y, c1); fma4(acc[1], xbv.z, c1); fma4(acc[2], xbv.w, c1);
                fma4(acc[3], xc.x, c1); fma4(acc[4], xc.y, c1);
                fma4(acc[0], xc.z, c2); fma4(acc[1], xc.w, c2); fma4(acc[2], xd.x, c2);
                fma4(acc[3], xd.y, c2); fma4(acc[4], xd.z, c2);
                fma4(acc[0], xd.w, c3); fma4(acc[1], xe.x, c3); fma4(acc[2], xe.y, c3);
                fma4(acc[3], xe.z, c3); fma4(acc[4], xe.w, c3);
            }
        }
        __syncthreads();   // drains DMA(s+1), publishes buf for next stage

        // ---- per-rowgroup epilogue after the 2nd channel ----
        if (cpr == 1) {
            const int ncols = g ? 5 : 4;
            const int npair = g ? 3 : 2;
            const int n = rowbase + rg * 16 + r;
            for (int p = 0; p < npair; ++p) {
                const int nc2 = (2 * p + 1 < ncols) ? 2 : 1;
                *(float4*)&lds[REDO + (wv * 2 + 0) * 256 + lane * 4] = acc[2 * p];
                if (nc2 > 1)
                    *(float4*)&lds[REDO + (wv * 2 + 1) * 256 + lane * 4] = acc[2 * p + 1];
                __syncthreads();
                if (wv < nc2) {
                    float4 v0 = LD4(REDO + (0 * 2 + wv) * 256 + lane * 4);
                    float4 v1 = LD4(REDO + (1 * 2 + wv) * 256 + lane * 4);
                    float4 v2 = LD4(REDO + (2 * 2 + wv) * 256 + lane * 4);
                    float4 v3 = LD4(REDO + (3 * 2 + wv) * 256 + lane * 4);
                    float4 v = make_float4(v0.x + v1.x + v2.x + v3.x,
                                           v0.y + v1.y + v2.y + v3.y,
                                           v0.z + v1.z + v2.z + v3.z,
                                           v0.w + v1.w + v2.w + v3.w);
                    const int col = 2 * p + wv;
                    if (!ATOMIC) {
                        float* wp = ws + (size_t)(cp * 9 + gb + col) * PLANE
                                       + (size_t)n * 16 + oq * 4;
                        *(float4*)wp = v;
                    } else {
                        const float sc = 1.0f / 32.0f;
                        float* op = ws + ((size_t)n * 16 + oq * 4) * 9 + gb + col;
                        atomicAdd(op + 0 * 9, v.x * sc);
                        atomicAdd(op + 1 * 9, v.y * sc);
                        atomicAdd(op + 2 * 9, v.z * sc);
                        atomicAdd(op + 3 * 9, v.w * sc);
                    }
                }
                if (p + 1 < npair) __syncthreads();
            }
        }
    }
#undef LD4
}

__global__ __launch_bounds__(256) void glin_reduce(const float* __restrict__ ws,
                                                   float* __restrict__ out) {
    const int idx = blockIdx.x * 256 + threadIdx.x;   // n*16 + o
    const float sc = 1.0f / 32.0f;
#pragma unroll
    for (int pc = 0; pc < 9; ++pc) {
        float v = 0.f;
#pragma unroll
        for (int c8 = 0; c8 < 8; ++c8)
            v += ws[(size_t)(c8 * 9 + pc) * PLANE + idx];
        out[(size_t)idx * 9 + pc] = v * sc;
    }
}

extern "C" void kernel_launch(void* const* d_in, const int* in_sizes, int n_in,
                              void* d_out, int out_size, void* d_ws, size_t ws_size,
                              hipStream_t stream) {
    const float* x  = (const float*)d_in[0];
    const float* w0 = (const float*)d_in[1];
    const float* w1 = (const float*)d_in[2];
    const float* w2 = (const float*)d_in[3];
    float* out = (float*)d_out;

    const size_t need = (size_t)8 * 9 * PLANE * sizeof(float);   // 37.75 MB
    if (d_ws != nullptr && ws_size >= need) {
        glin_main<false><<<512, 256, 0, stream>>>(x, w0, w1, w2, (float*)d_ws);
        glin_reduce<<<PLANE / 256, 256, 0, stream>>>((const float*)d_ws, out);
    } else {
        hipMemsetAsync(d_out, 0, (size_t)out_size * sizeof(float), stream);
        glin_main<true><<<512, 256, 0, stream>>>(x, w0, w1, w2, out);
    }
}